// Round 5
// baseline (635.455 us; speedup 1.0000x reference)
//
#include <hip/hip_runtime.h>
#include <math.h>

#define PI_D 3.14159265358979323846

// N=10 images, E=64 ch, H=128, W=256, M=16 modes, L=4 layers

typedef _Float16 h8 __attribute__((ext_vector_type(8)));
typedef float f16v __attribute__((ext_vector_type(16)));

__device__ __forceinline__ float gelu_f(float v){
  return 0.5f*v*(1.0f + erff(v*0.70710678118654752440f));
}

// ---------------- tables ----------------
__global__ __launch_bounds__(256) void k_tables(float* __restrict__ twFwH, float* __restrict__ twBwH,
                                                _Float16* __restrict__ Tspec, _Float16* __restrict__ TdftW){
  int id = blockIdx.x*256 + threadIdx.x;
  if (id < 4096){
    int h = id >> 5, m = id & 31;
    int xm = (m < 16) ? m : (96 + m);
    double ang = -2.0*PI_D*(double)((xm*h) & 127)/128.0;
    twFwH[id*2]   = (float)cos(ang);
    twFwH[id*2+1] = (float)sin(ang);
  } else if (id < 8192){
    int j = id - 4096;
    int m = j >> 7, h = j & 127;
    int xm = (m < 16) ? m : (96 + m);
    double ang = 2.0*PI_D*(double)((xm*h) & 127)/128.0;
    twBwH[j*2]   = (float)cos(ang);
    twBwH[j*2+1] = (float)sin(ang);
  } else if (id < 16384){
    int j = id - 8192;
    int w = j >> 5, kk = j & 31;
    int y = kk >> 1;
    double ang = 2.0*PI_D*(double)((w*y) & 255)/256.0;
    double v = (kk & 1) ? -sin(ang) : cos(ang);
    Tspec[j] = (_Float16)v;
  } else if (id < 24576){
    int j = id - 16384;
    int y2 = j >> 8, w = j & 255;
    int y = y2 >> 1;
    double ang = -2.0*PI_D*(double)((w*y) & 255)/256.0;
    double v = (y2 & 1) ? sin(ang) : cos(ang);
    TdftW[j] = (_Float16)v;
  }
}

// ---------------- fold updim into collapsed conv: Keff[o][rs*4+tap][4] = {c0,c1,kb,0} ----------------
__global__ __launch_bounds__(256) void k_foldK(const float* __restrict__ smw, const float* __restrict__ upw,
                                               const float* __restrict__ upb, float* __restrict__ Keff){
  int id = blockIdx.x*256 + threadIdx.x; // 0..1023 = o*16 + rs*4 + tap
  if (id >= 1024) return;
  int o = id >> 4, rs = (id >> 2) & 3, tap = id & 3;
  int r = rs >> 1, s = rs & 1, a = tap >> 1, b = tap & 1;
  int klo = (r==0) ? (a==0?0:1) : (a==0?0:2);
  int khi = (r==0) ? (a==0?0:2) : (a==0?1:2);
  int llo = (s==0) ? (b==0?0:1) : (b==0?0:2);
  int lhi = (s==0) ? (b==0?0:2) : (b==0?1:2);
  float a0=0.f, a1=0.f, ab=0.f;
  for (int i=0;i<64;++i){
    float t = 0.f;
    for (int kh=klo; kh<=khi; ++kh)
      for (int kw=llo; kw<=lhi; ++kw)
        t += smw[((size_t)o*64+i)*9 + kh*3+kw];
    a0 += t*upw[i*2];
    a1 += t*upw[i*2+1];
    ab += t*upb[i];
  }
  *(float4*)(Keff + o*64 + (rs*4+tap)*4) = make_float4(a0, a1, ab, 0.f);
}

// ---------------- fused updim+conv statistics over all 4 parities ----------------
// grid 640 = n*64 + pg (2 output rows per block); 256 threads = q
// Each thread accumulates 2 rows x 4 parities per o before the 64-lane butterfly,
// halving total cross-lane (ds_swizzle) traffic vs the 1-row version.
__global__ __launch_bounds__(256) void k_statconv(const float* __restrict__ sv,
                                                  const float* __restrict__ Keff,
                                                  float* __restrict__ part){
  __shared__ float SV[8*260]; // [dr 4][ch 2][260]
  int bid = blockIdx.x;
  int p0 = (bid & 63)*2, n = bid >> 6;
  int tid = threadIdx.x;
  for (int t = tid; t < 2080; t += 256){
    int dr = t / 520;
    int rem = t - dr*520;
    int ch = rem / 260;
    int ci = rem - ch*260;
    int row = p0 - 1 + dr;
    int col = ci - 1;
    float v = 0.f;
    if (row >= 0 && row < 128 && col >= 0 && col < 256)
      v = sv[((size_t)(n*2+ch)*128 + row)*256 + col];
    SV[(dr*2+ch)*260 + ci] = v;
  }
  __syncthreads();

  int q = tid;
  int lane = tid & 63, wid = tid >> 6;
  float x0[12], x1[12], ib[12];
  float rowok[4], colok[3];
  rowok[0] = (p0>0)?1.f:0.f; rowok[1]=1.f; rowok[2]=1.f; rowok[3] = (p0<126)?1.f:0.f;
  colok[0] = (q>0)?1.f:0.f; colok[1]=1.f; colok[2] = (q<255)?1.f:0.f;
  #pragma unroll
  for (int dr=0; dr<4; ++dr)
    #pragma unroll
    for (int dc=0; dc<3; ++dc){
      x0[dr*3+dc] = SV[(dr*2+0)*260 + q + dc];
      x1[dr*3+dc] = SV[(dr*2+1)*260 + q + dc];
      ib[dr*3+dc] = rowok[dr]*colok[dc];
    }

  float S1 = 0.f, S2 = 0.f;
  for (int o=0; o<64; ++o){
    const float4* kp = (const float4*)(Keff + o*64);   // uniform -> s_load
    float s1 = 0.f, s2 = 0.f;
    #pragma unroll
    for (int rr=0; rr<2; ++rr){                        // output row p0+rr
      #pragma unroll
      for (int r=0;r<2;++r){
        #pragma unroll
        for (int s=0;s<2;++s){
          float y = 0.f;
          #pragma unroll
          for (int a=0;a<2;++a){
            #pragma unroll
            for (int b=0;b<2;++b){
              float4 kv = kp[((r*2+s)*2+a)*2 + b];
              int d = (rr+r+a)*3 + (s+b);
              y += kv.x*x0[d] + kv.y*x1[d] + kv.z*ib[d];
            }
          }
          s1 += y; s2 += y*y;
        }
      }
    }
    #pragma unroll
    for (int m=1; m<64; m<<=1){
      s1 += __shfl_xor(s1, m, 64);
      s2 += __shfl_xor(s2, m, 64);
    }
    if (o == lane){ S1 = s1; S2 = s2; }
  }
  part[((size_t)bid*4 + wid)*128 + lane*2]   = S1;
  part[((size_t)bid*4 + wid)*128 + lane*2+1] = S2;
}

// ---------------- instance-norm statistics reduce ----------------
// 256 partials per (n,o): pg(64) x wave(4)
__global__ __launch_bounds__(256) void k_stats2(const float* __restrict__ part, float* __restrict__ stats){
  int n = blockIdx.x >> 6, o = blockIdx.x & 63;
  int idx = threadIdx.x;            // pg*4 + w
  int bid = n*64 + (idx >> 2);
  int w = idx & 3;
  double a1 = (double)part[((size_t)bid*4 + w)*128 + o*2];
  double a2 = (double)part[((size_t)bid*4 + w)*128 + o*2+1];
  __shared__ double r1[256], r2[256];
  r1[threadIdx.x]=a1; r2[threadIdx.x]=a2; __syncthreads();
  for (int st=128; st>0; st>>=1){
    if (threadIdx.x<st){ r1[threadIdx.x]+=r1[threadIdx.x+st]; r2[threadIdx.x]+=r2[threadIdx.x+st]; }
    __syncthreads();
  }
  if (threadIdx.x==0){
    double mu  = r1[0] / 131072.0;
    double var = r2[0] / 131072.0 - mu*mu;
    stats[blockIdx.x*2]   = (float)mu;
    stats[blockIdx.x*2+1] = (float)(1.0/sqrt(var + 1e-5));
  }
}

// ---------------- fused updim+conv (parity 0 only) + norm + gelu -> fp16 ----------------
// grid 1280 = n*128+p; 256 threads = q
__global__ __launch_bounds__(256) void k_convnorm(const float* __restrict__ sv,
                                                  const float* __restrict__ Keff,
                                                  const float* __restrict__ stats,
                                                  _Float16* __restrict__ act){
  __shared__ float SV[4*260]; // rows p-1,p x ch 2 x 260
  int bid = blockIdx.x;
  int p = bid & 127, n = bid >> 7;
  int tid = threadIdx.x;
  for (int t = tid; t < 1032; t += 256){
    int dr = t / 516;
    int rem = t - dr*516;
    int ch = rem / 258;
    int ci = rem - ch*258;
    int row = p - 1 + dr;
    int col = ci - 1;
    float v = 0.f;
    if (row >= 0 && col >= 0 && col < 256)
      v = sv[((size_t)(n*2+ch)*128 + row)*256 + col];
    SV[(dr*2+ch)*260 + ci] = v;
  }
  __syncthreads();

  int q = tid;
  float x0[4], x1[4], ib[4];
  float rowok0 = (p>0)?1.f:0.f;
  float colok0 = (q>0)?1.f:0.f;
  #pragma unroll
  for (int a=0;a<2;++a)
    #pragma unroll
    for (int b=0;b<2;++b){
      x0[a*2+b] = SV[(a*2+0)*260 + q + b];
      x1[a*2+b] = SV[(a*2+1)*260 + q + b];
      ib[a*2+b] = (a==0?rowok0:1.f) * (b==0?colok0:1.f);
    }

  for (int o=0; o<64; ++o){
    const float4* kp = (const float4*)(Keff + o*64);   // rs=0 slice at [0..3]
    float y = 0.f;
    #pragma unroll
    for (int t=0;t<4;++t){
      float4 kv = kp[t];
      y += kv.x*x0[t] + kv.y*x1[t] + kv.z*ib[t];
    }
    float mu = stats[(n*64+o)*2], istd = stats[(n*64+o)*2+1];
    float v = (y - mu)*istd;
    act[((size_t)(n*64+o)*128 + p)*256 + q] = (_Float16)gelu_f(v);
  }
}

// ---------------- forward DFT along W via MFMA ----------------
__global__ __launch_bounds__(256, 2) void k_dftW_mfma(const _Float16* __restrict__ act,
                                                      const _Float16* __restrict__ TdftW,
                                                      float* __restrict__ Cy){
  __shared__ _Float16 Ax[32768]; // [a 128][256] chunk-swizzled
  __shared__ _Float16 Bt[8192];  // [y2 32][256] chunk-swizzled
  int tid = threadIdx.x;
  int hp = blockIdx.x & 63, n = blockIdx.x >> 6;
  int h0 = hp*2;

  {
    int a = tid >> 1;
    int ws = (tid & 1) * 128;
    int e = a & 63, ht = a >> 6;
    const _Float16* src = act + ((size_t)(n*64+e))*32768 + (size_t)(h0+ht)*256 + ws;
    #pragma unroll
    for (int k=0;k<16;++k){
      h8 v = *(const h8*)(src + k*8);
      int wq = (ws >> 3) + k;
      int chunk = wq ^ (a & 7);
      *(h8*)(Ax + a*256 + chunk*8) = v;
    }
  }
  {
    int y2 = tid & 31, ws = (tid >> 5) * 32;
    const _Float16* src = TdftW + y2*256 + ws;
    #pragma unroll
    for (int k=0;k<4;++k){
      h8 v = *(const h8*)(src + k*8);
      int wq = (ws >> 3) + k;
      int chunk = wq ^ (y2 & 7);
      *(h8*)(Bt + y2*256 + chunk*8) = v;
    }
  }
  __syncthreads();

  int lane = tid & 63;
  int l31 = lane & 31, l5 = lane >> 5;
  int mt = tid >> 6;
  int a = mt*32 + l31;

  f16v acc;
  #pragma unroll
  for (int j=0;j<16;++j) acc[j] = 0.f;
  #pragma unroll
  for (int ks=0;ks<16;++ks){
    int kb = ks*16 + l5*8;
    int cA = (kb>>3) ^ (a & 7);
    int cB = (kb>>3) ^ (l31 & 7);
    h8 af = *(const h8*)(Ax + a*256 + cA*8);
    h8 bf = *(const h8*)(Bt + l31*256 + cB*8);
    acc = __builtin_amdgcn_mfma_f32_32x32x16_f16(af, bf, acc, 0,0,0);
  }
  #pragma unroll
  for (int j=0;j<16;++j){
    int arow = mt*32 + (j&3) + 8*(j>>2) + 4*l5;
    int ht = arow >> 6, e = arow & 63;
    Cy[((size_t)(n*64+e)*128 + h0+ht)*32 + l31] = acc[j];
  }
}

// ---------------- forward DFT along H (32 modes) ----------------
__global__ __launch_bounds__(256) void k_dftH(const float* __restrict__ Cy, const float* __restrict__ twg,
                                              float* __restrict__ coeff){
  __shared__ float CS[128*32];
  __shared__ float TW[128*64];
  int tid = threadIdx.x;
  size_t base = (size_t)blockIdx.x * 4096;
  for (int t=tid; t<4096; t+=256) CS[t] = Cy[base + t];
  for (int t=tid; t<8192; t+=256) TW[t] = twg[t];
  __syncthreads();
  int m = tid >> 3, yg = tid & 7;
  float c0r=0.f,c0i=0.f,c1r=0.f,c1i=0.f;
  for (int h=0; h<128; ++h){
    float2 tw = *(const float2*)(TW + h*64 + m*2);
    float2 v0 = *(const float2*)(CS + h*32 + yg*4);
    float2 v1 = *(const float2*)(CS + h*32 + yg*4 + 2);
    c0r += v0.x*tw.x - v0.y*tw.y;
    c0i += v0.x*tw.y + v0.y*tw.x;
    c1r += v1.x*tw.x - v1.y*tw.y;
    c1i += v1.x*tw.y + v1.y*tw.x;
  }
  size_t ob = (size_t)blockIdx.x*1024 + m*32 + yg*4;
  *(float2*)(coeff+ob)   = make_float2(c0r,c0i);
  *(float2*)(coeff+ob+2) = make_float2(c1r,c1i);
}

// ---------------- spectral mode mixing ----------------
__global__ __launch_bounds__(256) void k_modemix(const float* __restrict__ coeff,
                                                 const float* __restrict__ wr, const float* __restrict__ wi,
                                                 float* __restrict__ mo){
  __shared__ float CS[5*64*32];
  int bid = blockIdx.x;
  int ng = bid & 1;
  int oq = (bid >> 1) & 3;
  int m  = bid >> 3;
  int blk = m >> 4, mm = m & 15;
  int n0 = ng*5;
  int tid = threadIdx.x;
  for (int t=tid; t<2560; t+=256){
    int ni = t >> 3, prt = t & 7;
    int nn = ni >> 6, i = ni & 63;
    *(float4*)(CS + (nn*64+i)*32 + prt*4) =
      *(const float4*)(coeff + ((size_t)((n0+nn)*64+i)*32 + m)*32 + prt*4);
  }
  __syncthreads();
  int ty = tid >> 4, y = tid & 15;
  int o = oq*16 + ty;
  float ar[5], ai[5];
  #pragma unroll
  for (int nn=0;nn<5;++nn){ ar[nn]=0.f; ai[nn]=0.f; }
  const float* wrb = wr + ((size_t)(blk*64)*64 + o)*256 + mm*16 + y;
  const float* wib = wi + ((size_t)(blk*64)*64 + o)*256 + mm*16 + y;
  for (int i=0;i<64;++i){
    float wrv = wrb[(size_t)i*16384];
    float wiv = wib[(size_t)i*16384];
    const float* cp = CS + i*32 + y*2;
    #pragma unroll
    for (int nn=0;nn<5;++nn){
      float2 c2 = *(const float2*)(cp + nn*2048);
      ar[nn] += c2.x*wrv - c2.y*wiv;
      ai[nn] += c2.x*wiv + c2.y*wrv;
    }
  }
  #pragma unroll
  for (int nn=0;nn<5;++nn)
    *(float2*)(mo + (((size_t)((n0+nn)*64+o)*32 + m)*16 + y)*2) = make_float2(ar[nn], ai[nn]);
}

// ---------------- inverse DFT along H ----------------
__global__ __launch_bounds__(256) void k_idftH(const float* __restrict__ mo, const float* __restrict__ twg,
                                               float* __restrict__ G){
  __shared__ float MS[1024];
  __shared__ float TW[8192];
  int tid = threadIdx.x;
  size_t base = (size_t)blockIdx.x * 1024;
  for (int t=tid; t<1024; t+=256) MS[t] = mo[base + t];
  for (int t=tid; t<8192; t+=256) TW[t] = twg[t];
  __syncthreads();
  int y = tid & 15, hg = tid >> 4;
  float gr[8], gi[8];
  #pragma unroll
  for (int k=0;k<8;++k){ gr[k]=0.f; gi[k]=0.f; }
  for (int mI=0;mI<32;++mI){
    float2 c = *(const float2*)(MS + mI*32 + y*2);
    const float* twp = TW + mI*256 + hg*16;
    #pragma unroll
    for (int k=0;k<8;++k){
      float2 tw = *(const float2*)(twp + k*2);
      gr[k] += c.x*tw.x - c.y*tw.y;
      gi[k] += c.x*tw.y + c.y*tw.x;
    }
  }
  float f = (y==0) ? (1.f/32768.f) : (2.f/32768.f);
  #pragma unroll
  for (int k=0;k<8;++k){
    int h = hg*8+k;
    *(float2*)(G + ((size_t)blockIdx.x*128 + h)*32 + y*2) = make_float2(gr[k]*f, gi[k]*f);
  }
}

// ---------------- fused skip-GEMM + inverse DFT-W + gelu via MFMA ----------------
__global__ __launch_bounds__(256, 2) void k_combine_mfma(const _Float16* __restrict__ act_in,
                                                         const float* __restrict__ G,
                                                         const _Float16* __restrict__ Tspec,
                                                         const float* __restrict__ cw,
                                                         const float* __restrict__ cb,
                                                         _Float16* __restrict__ act_out){
  __shared__ _Float16 Bx[32768]; // [w 256][k 128] chunk-swizzled
  __shared__ _Float16 At[8192];  // [o 64][k 128] chunk-swizzled
  int tid = threadIdx.x;
  int h = blockIdx.x & 127, n = blockIdx.x >> 7;

  {
    int p = tid >> 3;
    int wl = tid & 7;
    int i0 = 2*p;
    const _Float16* r0 = act_in + (size_t)(n*64+i0)*32768 + (size_t)h*256;
    const _Float16* r1 = r0 + 32768;
    int cbase = (p >> 2);
    #pragma unroll
    for (int jj=0; jj<32; ++jj){
      int w = wl + 8*jj;
      union { _Float16 hh[2]; unsigned u; } pk;
      pk.hh[0] = r0[w]; pk.hh[1] = r1[w];
      int chunk = cbase ^ (w & 7);
      *(unsigned*)(Bx + w*128 + chunk*8 + (i0 & 7)) = pk.u;
    }
  }
  {
    int o = tid >> 2, seg = (tid & 3)*16;
    float4 c0 = *(const float4*)(cw + o*64 + seg);
    float4 c1 = *(const float4*)(cw + o*64 + seg + 4);
    float4 c2 = *(const float4*)(cw + o*64 + seg + 8);
    float4 c3 = *(const float4*)(cw + o*64 + seg + 12);
    h8 v0, v1;
    v0[0]=(_Float16)c0.x; v0[1]=(_Float16)c0.y; v0[2]=(_Float16)c0.z; v0[3]=(_Float16)c0.w;
    v0[4]=(_Float16)c1.x; v0[5]=(_Float16)c1.y; v0[6]=(_Float16)c1.z; v0[7]=(_Float16)c1.w;
    v1[0]=(_Float16)c2.x; v1[1]=(_Float16)c2.y; v1[2]=(_Float16)c2.z; v1[3]=(_Float16)c2.w;
    v1[4]=(_Float16)c3.x; v1[5]=(_Float16)c3.y; v1[6]=(_Float16)c3.z; v1[7]=(_Float16)c3.w;
    int cb0 = (seg>>3) ^ (o & 7);
    int cb1 = ((seg>>3)+1) ^ (o & 7);
    *(h8*)(At + o*128 + cb0*8) = v0;
    *(h8*)(At + o*128 + cb1*8) = v1;
  }
  {
    int o = tid >> 2, gq = tid & 3;
    const float* gp = G + ((size_t)(n*64+o)*128 + h)*32 + gq*8;
    float4 g0 = *(const float4*)(gp);
    float4 g1 = *(const float4*)(gp + 4);
    h8 v;
    v[0]=(_Float16)g0.x; v[1]=(_Float16)g0.y; v[2]=(_Float16)g0.z; v[3]=(_Float16)g0.w;
    v[4]=(_Float16)g1.x; v[5]=(_Float16)g1.y; v[6]=(_Float16)g1.z; v[7]=(_Float16)g1.w;
    int chunk = (8 + gq) ^ (o & 7);
    *(h8*)(At + o*128 + chunk*8) = v;
  }
  {
    int w = tid;
    const _Float16* tp = Tspec + w*32;
    #pragma unroll
    for (int cc=0; cc<4; ++cc){
      h8 v = *(const h8*)(tp + cc*8);
      int chunk = (8 + cc) ^ (w & 7);
      *(h8*)(Bx + w*128 + chunk*8) = v;
    }
  }
  __syncthreads();

  int lane = tid & 63;
  int l31 = lane & 31, l5 = lane >> 5;
  int w0 = tid >> 6;
  int mt = w0 & 1, ng = w0 >> 1;
  int o_lane = mt*32 + l31;

  h8 af[6];
  #pragma unroll
  for (int ks=0;ks<6;++ks){
    int kb = ks*16 + l5*8;
    int chunk = (kb>>3) ^ (o_lane & 7);
    af[ks] = *(const h8*)(At + o_lane*128 + chunk*8);
  }
  float bias[16];
  #pragma unroll
  for (int j=0;j<16;++j) bias[j] = cb[mt*32 + (j&3) + 8*(j>>2) + 4*l5];

  f16v acc[4];
  #pragma unroll
  for (int q=0;q<4;++q)
    #pragma unroll
    for (int j=0;j<16;++j) acc[q][j] = bias[j];

  #pragma unroll
  for (int q=0;q<4;++q){
    int w = (ng*4+q)*32 + l31;
    const _Float16* bbase = Bx + w*128;
    int w7 = w & 7;
    #pragma unroll
    for (int ks=0;ks<6;++ks){
      int kb = ks*16 + l5*8;
      int chunk = (kb>>3) ^ w7;
      h8 bf = *(const h8*)(bbase + chunk*8);
      acc[q] = __builtin_amdgcn_mfma_f32_32x32x16_f16(af[ks], bf, acc[q], 0,0,0);
    }
  }

  #pragma unroll
  for (int q=0;q<4;++q){
    int wcol = (ng*4+q)*32 + l31;
    #pragma unroll
    for (int j=0;j<16;++j){
      int o = mt*32 + (j&3) + 8*(j>>2) + 4*l5;
      float v = gelu_f(acc[q][j]);
      act_out[(size_t)(n*64+o)*32768 + (size_t)h*256 + wcol] = (_Float16)v;
    }
  }
}

// ---------------- downdim 1x1 conv (E=64 -> C=2), fp16 in ----------------
__global__ __launch_bounds__(256) void k_downdim(const _Float16* __restrict__ x, const float* __restrict__ wd,
                                                 const float* __restrict__ bd, float* __restrict__ out){
  size_t idx = (size_t)blockIdx.x*256 + threadIdx.x;
  int n = (int)(idx >> 15);
  int pos = (int)(idx & 32767);
  float a0 = bd[0], a1 = bd[1];
  const _Float16* xp = x + (size_t)n*2097152 + pos;
  for (int e=0;e<64;++e){
    float v = (float)xp[(size_t)e*32768];
    a0 += wd[e]*v;
    a1 += wd[64+e]*v;
  }
  out[(size_t)n*65536 + pos] = a0;
  out[(size_t)n*65536 + 32768 + pos] = a1;
}

extern "C" void kernel_launch(void* const* d_in, const int* in_sizes, int n_in,
                              void* d_out, int out_size, void* d_ws, size_t ws_size,
                              hipStream_t stream) {
  const float* sv  = (const float*)d_in[0];
  const float* upw = (const float*)d_in[1];
  const float* upb = (const float*)d_in[2];
  const float* smw = (const float*)d_in[3];
  const float* smb = (const float*)d_in[4];
  const float* fwr = (const float*)d_in[5];
  const float* fwi = (const float*)d_in[6];
  const float* fcw = (const float*)d_in[7];
  const float* fcb = (const float*)d_in[8];
  const float* ddw = (const float*)d_in[9];
  const float* ddb = (const float*)d_in[10];
  float* out = (float*)d_out;
  (void)smb; // smooth_b is spatially uniform per (n,o); instance-norm mean-subtraction cancels it exactly.

  float* W = (float*)d_ws;
  _Float16* actA = (_Float16*)W;                    // 20971520 halves
  _Float16* actB = (_Float16*)(W + 10485760);       // 20971520 halves
  float* Cy    = W + 20971520;                      // 2621440
  float* G     = W + 23592960;                      // 2621440
  float* coeff = W + 26214400;                      // 655360
  float* mo    = W + 26869760;                      // 655360
  float* part  = W + 27525120;                      // 655360 (327680 used)
  float* stats = W + 28180480;                      // 1280
  float* Keff  = W + 28181760;                      // 4096
  float* twFwH = W + 28185856;                      // 8192
  float* twBwH = W + 28194048;                      // 8192
  _Float16* Tspec = (_Float16*)(W + 28202240);      // 8192 halves
  _Float16* TdftW = (_Float16*)(W + 28206336);      // 8192 halves

  k_tables<<<96,256,0,stream>>>(twFwH, twBwH, Tspec, TdftW);
  k_foldK<<<4,256,0,stream>>>(smw, upw, upb, Keff);
  k_statconv<<<640,256,0,stream>>>(sv, Keff, part);
  k_stats2<<<640,256,0,stream>>>(part, stats);
  k_convnorm<<<1280,256,0,stream>>>(sv, Keff, stats, actA);

  _Float16* xa = actA; _Float16* xb = actB;
  for (int l=0;l<4;++l){
    k_dftW_mfma<<<640,256,0,stream>>>(xa, TdftW, Cy);
    k_dftH<<<640,256,0,stream>>>(Cy, twFwH, coeff);
    k_modemix<<<256,256,0,stream>>>(coeff, fwr + (size_t)l*2097152, fwi + (size_t)l*2097152, mo);
    k_idftH<<<640,256,0,stream>>>(mo, twBwH, G);
    k_combine_mfma<<<1280,256,0,stream>>>(xa, G, Tspec, fcw + (size_t)l*4096, fcb + (size_t)l*64, xb);
    _Float16* t = xa; xa = xb; xb = t;
  }
  k_downdim<<<1280,256,0,stream>>>(xa, ddw, ddb, out);
}

// Round 6
// 602.921 us; speedup vs baseline: 1.0540x; 1.0540x over previous
//
#include <hip/hip_runtime.h>
#include <math.h>

#define PI_D 3.14159265358979323846

// N=10 images, E=64 ch, H=128, W=256, M=16 modes, L=4 layers

typedef _Float16 h8 __attribute__((ext_vector_type(8)));
typedef float f16v __attribute__((ext_vector_type(16)));

__device__ __forceinline__ float gelu_f(float v){
  return 0.5f*v*(1.0f + erff(v*0.70710678118654752440f));
}

// ---------------- tables ----------------
__global__ __launch_bounds__(256) void k_tables(float* __restrict__ twFwH, float* __restrict__ twBwH,
                                                _Float16* __restrict__ Tspec, _Float16* __restrict__ TdftW){
  int id = blockIdx.x*256 + threadIdx.x;
  if (id < 4096){
    int h = id >> 5, m = id & 31;
    int xm = (m < 16) ? m : (96 + m);
    double ang = -2.0*PI_D*(double)((xm*h) & 127)/128.0;
    twFwH[id*2]   = (float)cos(ang);
    twFwH[id*2+1] = (float)sin(ang);
  } else if (id < 8192){
    int j = id - 4096;
    int m = j >> 7, h = j & 127;
    int xm = (m < 16) ? m : (96 + m);
    double ang = 2.0*PI_D*(double)((xm*h) & 127)/128.0;
    twBwH[j*2]   = (float)cos(ang);
    twBwH[j*2+1] = (float)sin(ang);
  } else if (id < 16384){
    int j = id - 8192;
    int w = j >> 5, kk = j & 31;
    int y = kk >> 1;
    double ang = 2.0*PI_D*(double)((w*y) & 255)/256.0;
    double v = (kk & 1) ? -sin(ang) : cos(ang);
    Tspec[j] = (_Float16)v;
  } else if (id < 24576){
    int j = id - 16384;
    int y2 = j >> 8, w = j & 255;
    int y = y2 >> 1;
    double ang = -2.0*PI_D*(double)((w*y) & 255)/256.0;
    double v = (y2 & 1) ? sin(ang) : cos(ang);
    TdftW[j] = (_Float16)v;
  }
}

// ---------------- fold updim into collapsed conv: Keff[o][rs*4+tap][4] = {c0,c1,kb,0} ----------------
__global__ __launch_bounds__(256) void k_foldK(const float* __restrict__ smw, const float* __restrict__ upw,
                                               const float* __restrict__ upb, float* __restrict__ Keff){
  int id = blockIdx.x*256 + threadIdx.x; // 0..1023 = o*16 + rs*4 + tap
  if (id >= 1024) return;
  int o = id >> 4, rs = (id >> 2) & 3, tap = id & 3;
  int r = rs >> 1, s = rs & 1, a = tap >> 1, b = tap & 1;
  int klo = (r==0) ? (a==0?0:1) : (a==0?0:2);
  int khi = (r==0) ? (a==0?0:2) : (a==0?1:2);
  int llo = (s==0) ? (b==0?0:1) : (b==0?0:2);
  int lhi = (s==0) ? (b==0?0:2) : (b==0?1:2);
  float a0=0.f, a1=0.f, ab=0.f;
  for (int i=0;i<64;++i){
    float t = 0.f;
    for (int kh=klo; kh<=khi; ++kh)
      for (int kw=llo; kw<=lhi; ++kw)
        t += smw[((size_t)o*64+i)*9 + kh*3+kw];
    a0 += t*upw[i*2];
    a1 += t*upw[i*2+1];
    ab += t*upb[i];
  }
  *(float4*)(Keff + o*64 + (rs*4+tap)*4) = make_float4(a0, a1, ab, 0.f);
}

// ---------------- one-shot weight transpose: wr/wi -> Wt fp16 [l][blk][my][i][o](r,i) ----------------
// grid 512 = l(4) x blk(2) x i(64); 256 threads = my
__global__ __launch_bounds__(256) void k_transW(const float* __restrict__ wr, const float* __restrict__ wi,
                                                unsigned* __restrict__ Wt){
  __shared__ unsigned P[64*257];
  int lb = blockIdx.x;
  int i = lb & 63, blk = (lb>>6)&1, l = lb>>7;
  int tid = threadIdx.x;     // my = mm*16+y
  size_t sbase = (size_t)l*2097152 + (size_t)blk*1048576 + (size_t)i*16384 + tid;
  for (int o=0;o<64;++o){
    float a = wr[sbase + (size_t)o*256];
    float b = wi[sbase + (size_t)o*256];
    union { unsigned u; _Float16 h[2]; } pk;
    pk.h[0] = (_Float16)a; pk.h[1] = (_Float16)b;
    P[o*257 + tid] = pk.u;
  }
  __syncthreads();
  int o = tid & 63, g = tid >> 6;
  size_t dbase = (size_t)(l*2+blk)*1048576;   // 256 my * 4096
  for (int it=0; it<64; ++it){
    int my = g*64 + it;
    Wt[dbase + (size_t)my*4096 + i*64 + o] = P[o*257 + my];
  }
}

// ---------------- fused updim+conv statistics, lane = o (no shuffles) ----------------
// grid 640 = n*64 + pg (2 rows); 4 waves = (row-in-pair x col-half); lanes = 64 o
__global__ __launch_bounds__(256) void k_statconv(const float* __restrict__ sv,
                                                  const float* __restrict__ Keff,
                                                  float* __restrict__ part){
  __shared__ __align__(16) float SV[8*264]; // [row 4][ch 2][264]
  int bid = blockIdx.x;
  int p0 = (bid & 63)*2, n = bid >> 6;
  int tid = threadIdx.x;
  for (int t = tid; t < 2080; t += 256){
    int dr = t / 520; int rem = t - dr*520; int ch = rem / 260; int ci = rem - ch*260;
    int row = p0 - 1 + dr, col = ci - 1;
    float v = 0.f;
    if (row >= 0 && row < 128 && col >= 0 && col < 256)
      v = sv[((size_t)(n*2+ch)*128 + row)*256 + col];
    SV[(dr*2+ch)*264 + ci] = v;
  }
  __syncthreads();
  int lane = tid & 63, wid = tid >> 6;
  int pr = wid >> 1;
  int p = p0 + pr;
  int c0 = (wid & 1) * 128;
  float kx[16], ky[16], kz[16];
  #pragma unroll
  for (int t2=0;t2<16;++t2){
    float4 kv = *(const float4*)(Keff + lane*64 + t2*4);
    kx[t2]=kv.x; ky[t2]=kv.y; kz[t2]=kv.z;
  }
  float kzs[4];
  #pragma unroll
  for (int rs=0;rs<4;++rs)
    kzs[rs] = kz[rs*4]+kz[rs*4+1]+kz[rs*4+2]+kz[rs*4+3];
  bool rowedge = (p==0) || (p==127);
  float rok[3]; rok[0] = (p>0)?1.f:0.f; rok[1]=1.f; rok[2]=(p<127)?1.f:0.f;
  float s1=0.f, s2=0.f;
  for (int gq=0; gq<32; ++gq){
    int qq0 = c0 + gq*4;
    float X0[3][8], X1[3][8];
    #pragma unroll
    for (int dr=0; dr<3; ++dr){
      const float* r0 = SV + ((pr+dr)*2+0)*264 + qq0;
      const float* r1 = SV + ((pr+dr)*2+1)*264 + qq0;
      float4 a = *(const float4*)r0, b = *(const float4*)(r0+4);
      float4 cc = *(const float4*)r1, d = *(const float4*)(r1+4);
      X0[dr][0]=a.x;X0[dr][1]=a.y;X0[dr][2]=a.z;X0[dr][3]=a.w;
      X0[dr][4]=b.x;X0[dr][5]=b.y;X0[dr][6]=b.z;X0[dr][7]=b.w;
      X1[dr][0]=cc.x;X1[dr][1]=cc.y;X1[dr][2]=cc.z;X1[dr][3]=cc.w;
      X1[dr][4]=d.x;X1[dr][5]=d.y;X1[dr][6]=d.z;X1[dr][7]=d.w;
    }
    bool coledge = (qq0 == 0) || (qq0 == 252);
    if (!coledge && !rowedge){
      #pragma unroll
      for (int j=0;j<4;++j){
        #pragma unroll
        for (int rs=0;rs<4;++rs){
          int r = rs>>1, s = rs&1;
          float y = kzs[rs];
          #pragma unroll
          for (int a2=0;a2<2;++a2)
            #pragma unroll
            for (int b2=0;b2<2;++b2){
              int t2 = rs*4 + a2*2 + b2;
              y += kx[t2]*X0[r+a2][j+s+b2] + ky[t2]*X1[r+a2][j+s+b2];
            }
          s1 += y; s2 = fmaf(y,y,s2);
        }
      }
    } else {
      #pragma unroll
      for (int j=0;j<4;++j){
        int col = qq0 + j;
        float cok[3]; cok[0]=(col>0)?1.f:0.f; cok[1]=1.f; cok[2]=(col<255)?1.f:0.f;
        #pragma unroll
        for (int rs=0;rs<4;++rs){
          int r = rs>>1, s = rs&1;
          float y = 0.f;
          #pragma unroll
          for (int a2=0;a2<2;++a2)
            #pragma unroll
            for (int b2=0;b2<2;++b2){
              int t2 = rs*4 + a2*2 + b2;
              y += kx[t2]*X0[r+a2][j+s+b2] + ky[t2]*X1[r+a2][j+s+b2] + kz[t2]*(rok[r+a2]*cok[s+b2]);
            }
          s1 += y; s2 = fmaf(y,y,s2);
        }
      }
    }
  }
  part[((size_t)(bid*4 + wid))*128 + lane*2]   = s1;
  part[((size_t)(bid*4 + wid))*128 + lane*2+1] = s2;
}

// ---------------- instance-norm statistics reduce ----------------
__global__ __launch_bounds__(256) void k_stats2(const float* __restrict__ part, float* __restrict__ stats){
  int n = blockIdx.x >> 6, o = blockIdx.x & 63;
  int idx = threadIdx.x;            // pg*4 + w
  int bid = n*64 + (idx >> 2);
  int w = idx & 3;
  double a1 = (double)part[((size_t)(bid*4 + w))*128 + o*2];
  double a2 = (double)part[((size_t)(bid*4 + w))*128 + o*2+1];
  __shared__ double r1[256], r2[256];
  r1[threadIdx.x]=a1; r2[threadIdx.x]=a2; __syncthreads();
  for (int st=128; st>0; st>>=1){
    if (threadIdx.x<st){ r1[threadIdx.x]+=r1[threadIdx.x+st]; r2[threadIdx.x]+=r2[threadIdx.x+st]; }
    __syncthreads();
  }
  if (threadIdx.x==0){
    double mu  = r1[0] / 131072.0;
    double var = r2[0] / 131072.0 - mu*mu;
    stats[blockIdx.x*2]   = (float)mu;
    stats[blockIdx.x*2+1] = (float)(1.0/sqrt(var + 1e-5));
  }
}

// ---------------- fused updim+conv (parity 0 only) + norm + gelu -> fp16 ----------------
__global__ __launch_bounds__(256) void k_convnorm(const float* __restrict__ sv,
                                                  const float* __restrict__ Keff,
                                                  const float* __restrict__ stats,
                                                  _Float16* __restrict__ act){
  __shared__ float SV[4*260];
  int bid = blockIdx.x;
  int p = bid & 127, n = bid >> 7;
  int tid = threadIdx.x;
  for (int t = tid; t < 1032; t += 256){
    int dr = t / 516;
    int rem = t - dr*516;
    int ch = rem / 258;
    int ci = rem - ch*258;
    int row = p - 1 + dr;
    int col = ci - 1;
    float v = 0.f;
    if (row >= 0 && col >= 0 && col < 256)
      v = sv[((size_t)(n*2+ch)*128 + row)*256 + col];
    SV[(dr*2+ch)*260 + ci] = v;
  }
  __syncthreads();

  int q = tid;
  float x0[4], x1[4], ib[4];
  float rowok0 = (p>0)?1.f:0.f;
  float colok0 = (q>0)?1.f:0.f;
  #pragma unroll
  for (int a=0;a<2;++a)
    #pragma unroll
    for (int b=0;b<2;++b){
      x0[a*2+b] = SV[(a*2+0)*260 + q + b];
      x1[a*2+b] = SV[(a*2+1)*260 + q + b];
      ib[a*2+b] = (a==0?rowok0:1.f) * (b==0?colok0:1.f);
    }

  for (int o=0; o<64; ++o){
    const float4* kp = (const float4*)(Keff + o*64);
    float y = 0.f;
    #pragma unroll
    for (int t=0;t<4;++t){
      float4 kv = kp[t];
      y += kv.x*x0[t] + kv.y*x1[t] + kv.z*ib[t];
    }
    float mu = stats[(n*64+o)*2], istd = stats[(n*64+o)*2+1];
    float v = (y - mu)*istd;
    act[((size_t)(n*64+o)*128 + p)*256 + q] = (_Float16)gelu_f(v);
  }
}

// ---------------- forward DFT along W via MFMA ----------------
__global__ __launch_bounds__(256, 2) void k_dftW_mfma(const _Float16* __restrict__ act,
                                                      const _Float16* __restrict__ TdftW,
                                                      float* __restrict__ Cy){
  __shared__ _Float16 Ax[32768];
  __shared__ _Float16 Bt[8192];
  int tid = threadIdx.x;
  int hp = blockIdx.x & 63, n = blockIdx.x >> 6;
  int h0 = hp*2;

  {
    int a = tid >> 1;
    int ws = (tid & 1) * 128;
    int e = a & 63, ht = a >> 6;
    const _Float16* src = act + ((size_t)(n*64+e))*32768 + (size_t)(h0+ht)*256 + ws;
    #pragma unroll
    for (int k=0;k<16;++k){
      h8 v = *(const h8*)(src + k*8);
      int wq = (ws >> 3) + k;
      int chunk = wq ^ (a & 7);
      *(h8*)(Ax + a*256 + chunk*8) = v;
    }
  }
  {
    int y2 = tid & 31, ws = (tid >> 5) * 32;
    const _Float16* src = TdftW + y2*256 + ws;
    #pragma unroll
    for (int k=0;k<4;++k){
      h8 v = *(const h8*)(src + k*8);
      int wq = (ws >> 3) + k;
      int chunk = wq ^ (y2 & 7);
      *(h8*)(Bt + y2*256 + chunk*8) = v;
    }
  }
  __syncthreads();

  int lane = tid & 63;
  int l31 = lane & 31, l5 = lane >> 5;
  int mt = tid >> 6;
  int a = mt*32 + l31;

  f16v acc;
  #pragma unroll
  for (int j=0;j<16;++j) acc[j] = 0.f;
  #pragma unroll
  for (int ks=0;ks<16;++ks){
    int kb = ks*16 + l5*8;
    int cA = (kb>>3) ^ (a & 7);
    int cB = (kb>>3) ^ (l31 & 7);
    h8 af = *(const h8*)(Ax + a*256 + cA*8);
    h8 bf = *(const h8*)(Bt + l31*256 + cB*8);
    acc = __builtin_amdgcn_mfma_f32_32x32x16_f16(af, bf, acc, 0,0,0);
  }
  #pragma unroll
  for (int j=0;j<16;++j){
    int arow = mt*32 + (j&3) + 8*(j>>2) + 4*l5;
    int ht = arow >> 6, e = arow & 63;
    Cy[((size_t)(n*64+e)*128 + h0+ht)*32 + l31] = acc[j];
  }
}

// ---------------- forward DFT along H (32 modes); coeff layout [m][y][n][e][2] ----------------
__global__ __launch_bounds__(256) void k_dftH(const float* __restrict__ Cy, const float* __restrict__ twg,
                                              float* __restrict__ coeff){
  __shared__ float CS[128*32];
  __shared__ float TW[128*64];
  int tid = threadIdx.x;
  size_t base = (size_t)blockIdx.x * 4096;
  for (int t=tid; t<4096; t+=256) CS[t] = Cy[base + t];
  for (int t=tid; t<8192; t+=256) TW[t] = twg[t];
  __syncthreads();
  int m = tid >> 3, yg = tid & 7;
  float c0r=0.f,c0i=0.f,c1r=0.f,c1i=0.f;
  for (int h=0; h<128; ++h){
    float2 tw = *(const float2*)(TW + h*64 + m*2);
    float2 v0 = *(const float2*)(CS + h*32 + yg*4);
    float2 v1 = *(const float2*)(CS + h*32 + yg*4 + 2);
    c0r += v0.x*tw.x - v0.y*tw.y;
    c0i += v0.x*tw.y + v0.y*tw.x;
    c1r += v1.x*tw.x - v1.y*tw.y;
    c1i += v1.x*tw.y + v1.y*tw.x;
  }
  int y0 = yg*2;
  size_t o0 = (size_t)(m*16 + y0)*1280 + (size_t)blockIdx.x*2;
  *(float2*)(coeff + o0)        = make_float2(c0r,c0i);
  *(float2*)(coeff + o0 + 1280) = make_float2(c1r,c1i);
}

// ---------------- spectral mode mixing via transposed fp16 weights ----------------
// grid 512 = blk(2) x mm(16) x y(16); mo layout [m][y][n][o][2]
__global__ __launch_bounds__(256) void k_modemix2(const float* __restrict__ coeff,
                                                  const unsigned* __restrict__ Wt,
                                                  float* __restrict__ mo, int l){
  __shared__ unsigned WS[4096];   // [i 64][o 64] packed (wr,wi) fp16
  __shared__ float CS[1280];      // [n 10][i 64][2]
  int bid = blockIdx.x;
  int y = bid & 15, mm = (bid>>4)&15, blk = bid>>8;
  int my = mm*16 + y;
  int tid = threadIdx.x;
  {
    const uint4* src = (const uint4*)(Wt + ((size_t)((l*2+blk)*256 + my))*4096);
    uint4* dst = (uint4*)WS;
    for (int t = tid; t < 1024; t += 256) dst[t] = src[t];
  }
  {
    const float* src = coeff + (size_t)(blk*256 + my)*1280;
    for (int t = tid; t < 1280; t += 256) CS[t] = src[t];
  }
  __syncthreads();
  int o = tid & 63, g = tid >> 6;
  int c = g & 1, nbase = g >> 1;         // n = nbase + 2k
  float acc[5] = {0.f,0.f,0.f,0.f,0.f};
  for (int i=0;i<64;++i){
    union { unsigned u; _Float16 h[2]; } pk;
    pk.u = WS[i*64 + o];
    float wr_f = (float)pk.h[0], wi_f = (float)pk.h[1];
    #pragma unroll
    for (int k=0;k<5;++k){
      int n = nbase + 2*k;
      float cr = CS[(n*64+i)*2], ci = CS[(n*64+i)*2+1];
      float a1 = c ? ci : cr;
      float a2 = c ? cr : -ci;
      acc[k] += wr_f*a1 + wi_f*a2;
    }
  }
  size_t obase = (size_t)(blk*256 + my)*1280;
  #pragma unroll
  for (int k=0;k<5;++k)
    mo[obase + (size_t)(nbase + 2*k)*128 + o*2 + c] = acc[k];
}

// ---------------- inverse DFT along H; mo layout [m][y][n][o][2] ----------------
__global__ __launch_bounds__(256) void k_idftH(const float* __restrict__ mo, const float* __restrict__ twg,
                                               float* __restrict__ G){
  __shared__ float MS[1024];
  __shared__ float TW[8192];
  int tid = threadIdx.x;
  for (int t=tid; t<1024; t+=256){
    int mI = t>>5, rem = t&31, yy = rem>>1, c = rem&1;
    MS[t] = mo[(size_t)(mI*16+yy)*1280 + (size_t)blockIdx.x*2 + c];
  }
  for (int t=tid; t<8192; t+=256) TW[t] = twg[t];
  __syncthreads();
  int y = tid & 15, hg = tid >> 4;
  float gr[8], gi[8];
  #pragma unroll
  for (int k=0;k<8;++k){ gr[k]=0.f; gi[k]=0.f; }
  for (int mI=0;mI<32;++mI){
    float2 c = *(const float2*)(MS + mI*32 + y*2);
    const float* twp = TW + mI*256 + hg*16;
    #pragma unroll
    for (int k=0;k<8;++k){
      float2 tw = *(const float2*)(twp + k*2);
      gr[k] += c.x*tw.x - c.y*tw.y;
      gi[k] += c.x*tw.y + c.y*tw.x;
    }
  }
  float f = (y==0) ? (1.f/32768.f) : (2.f/32768.f);
  #pragma unroll
  for (int k=0;k<8;++k){
    int h = hg*8+k;
    *(float2*)(G + ((size_t)blockIdx.x*128 + h)*32 + y*2) = make_float2(gr[k]*f, gi[k]*f);
  }
}

// ---------------- fused skip-GEMM + inverse DFT-W + gelu via MFMA ----------------
__global__ __launch_bounds__(256, 2) void k_combine_mfma(const _Float16* __restrict__ act_in,
                                                         const float* __restrict__ G,
                                                         const _Float16* __restrict__ Tspec,
                                                         const float* __restrict__ cw,
                                                         const float* __restrict__ cb,
                                                         _Float16* __restrict__ act_out){
  __shared__ _Float16 Bx[32768];
  __shared__ _Float16 At[8192];
  int tid = threadIdx.x;
  int h = blockIdx.x & 127, n = blockIdx.x >> 7;

  {
    int p = tid >> 3;
    int wl = tid & 7;
    int i0 = 2*p;
    const _Float16* r0 = act_in + (size_t)(n*64+i0)*32768 + (size_t)h*256;
    const _Float16* r1 = r0 + 32768;
    int cbase = (p >> 2);
    #pragma unroll
    for (int jj=0; jj<32; ++jj){
      int w = wl + 8*jj;
      union { _Float16 hh[2]; unsigned u; } pk;
      pk.hh[0] = r0[w]; pk.hh[1] = r1[w];
      int chunk = cbase ^ (w & 7);
      *(unsigned*)(Bx + w*128 + chunk*8 + (i0 & 7)) = pk.u;
    }
  }
  {
    int o = tid >> 2, seg = (tid & 3)*16;
    float4 c0 = *(const float4*)(cw + o*64 + seg);
    float4 c1 = *(const float4*)(cw + o*64 + seg + 4);
    float4 c2 = *(const float4*)(cw + o*64 + seg + 8);
    float4 c3 = *(const float4*)(cw + o*64 + seg + 12);
    h8 v0, v1;
    v0[0]=(_Float16)c0.x; v0[1]=(_Float16)c0.y; v0[2]=(_Float16)c0.z; v0[3]=(_Float16)c0.w;
    v0[4]=(_Float16)c1.x; v0[5]=(_Float16)c1.y; v0[6]=(_Float16)c1.z; v0[7]=(_Float16)c1.w;
    v1[0]=(_Float16)c2.x; v1[1]=(_Float16)c2.y; v1[2]=(_Float16)c2.z; v1[3]=(_Float16)c2.w;
    v1[4]=(_Float16)c3.x; v1[5]=(_Float16)c3.y; v1[6]=(_Float16)c3.z; v1[7]=(_Float16)c3.w;
    int cb0 = (seg>>3) ^ (o & 7);
    int cb1 = ((seg>>3)+1) ^ (o & 7);
    *(h8*)(At + o*128 + cb0*8) = v0;
    *(h8*)(At + o*128 + cb1*8) = v1;
  }
  {
    int o = tid >> 2, gq = tid & 3;
    const float* gp = G + ((size_t)(n*64+o)*128 + h)*32 + gq*8;
    float4 g0 = *(const float4*)(gp);
    float4 g1 = *(const float4*)(gp + 4);
    h8 v;
    v[0]=(_Float16)g0.x; v[1]=(_Float16)g0.y; v[2]=(_Float16)g0.z; v[3]=(_Float16)g0.w;
    v[4]=(_Float16)g1.x; v[5]=(_Float16)g1.y; v[6]=(_Float16)g1.z; v[7]=(_Float16)g1.w;
    int chunk = (8 + gq) ^ (o & 7);
    *(h8*)(At + o*128 + chunk*8) = v;
  }
  {
    int w = tid;
    const _Float16* tp = Tspec + w*32;
    #pragma unroll
    for (int cc=0; cc<4; ++cc){
      h8 v = *(const h8*)(tp + cc*8);
      int chunk = (8 + cc) ^ (w & 7);
      *(h8*)(Bx + w*128 + chunk*8) = v;
    }
  }
  __syncthreads();

  int lane = tid & 63;
  int l31 = lane & 31, l5 = lane >> 5;
  int w0 = tid >> 6;
  int mt = w0 & 1, ng = w0 >> 1;
  int o_lane = mt*32 + l31;

  h8 af[6];
  #pragma unroll
  for (int ks=0;ks<6;++ks){
    int kb = ks*16 + l5*8;
    int chunk = (kb>>3) ^ (o_lane & 7);
    af[ks] = *(const h8*)(At + o_lane*128 + chunk*8);
  }
  float bias[16];
  #pragma unroll
  for (int j=0;j<16;++j) bias[j] = cb[mt*32 + (j&3) + 8*(j>>2) + 4*l5];

  f16v acc[4];
  #pragma unroll
  for (int q=0;q<4;++q)
    #pragma unroll
    for (int j=0;j<16;++j) acc[q][j] = bias[j];

  #pragma unroll
  for (int q=0;q<4;++q){
    int w = (ng*4+q)*32 + l31;
    const _Float16* bbase = Bx + w*128;
    int w7 = w & 7;
    #pragma unroll
    for (int ks=0;ks<6;++ks){
      int kb = ks*16 + l5*8;
      int chunk = (kb>>3) ^ w7;
      h8 bf = *(const h8*)(bbase + chunk*8);
      acc[q] = __builtin_amdgcn_mfma_f32_32x32x16_f16(af[ks], bf, acc[q], 0,0,0);
    }
  }

  #pragma unroll
  for (int q=0;q<4;++q){
    int wcol = (ng*4+q)*32 + l31;
    #pragma unroll
    for (int j=0;j<16;++j){
      int o = mt*32 + (j&3) + 8*(j>>2) + 4*l5;
      float v = gelu_f(acc[q][j]);
      act_out[(size_t)(n*64+o)*32768 + (size_t)h*256 + wcol] = (_Float16)v;
    }
  }
}

// ---------------- downdim 1x1 conv (E=64 -> C=2), fp16 in ----------------
__global__ __launch_bounds__(256) void k_downdim(const _Float16* __restrict__ x, const float* __restrict__ wd,
                                                 const float* __restrict__ bd, float* __restrict__ out){
  size_t idx = (size_t)blockIdx.x*256 + threadIdx.x;
  int n = (int)(idx >> 15);
  int pos = (int)(idx & 32767);
  float a0 = bd[0], a1 = bd[1];
  const _Float16* xp = x + (size_t)n*2097152 + pos;
  for (int e=0;e<64;++e){
    float v = (float)xp[(size_t)e*32768];
    a0 += wd[e]*v;
    a1 += wd[64+e]*v;
  }
  out[(size_t)n*65536 + pos] = a0;
  out[(size_t)n*65536 + 32768 + pos] = a1;
}

extern "C" void kernel_launch(void* const* d_in, const int* in_sizes, int n_in,
                              void* d_out, int out_size, void* d_ws, size_t ws_size,
                              hipStream_t stream) {
  const float* sv  = (const float*)d_in[0];
  const float* upw = (const float*)d_in[1];
  const float* upb = (const float*)d_in[2];
  const float* smw = (const float*)d_in[3];
  const float* smb = (const float*)d_in[4];
  const float* fwr = (const float*)d_in[5];
  const float* fwi = (const float*)d_in[6];
  const float* fcw = (const float*)d_in[7];
  const float* fcb = (const float*)d_in[8];
  const float* ddw = (const float*)d_in[9];
  const float* ddb = (const float*)d_in[10];
  float* out = (float*)d_out;
  (void)smb; // spatially uniform per (n,o); cancelled exactly by instance-norm mean subtraction

  float* W = (float*)d_ws;
  _Float16* actA = (_Float16*)W;                    // 20971520 halves
  _Float16* actB = (_Float16*)(W + 10485760);       // 20971520 halves
  float* Cy    = W + 20971520;                      // 2621440
  float* G     = W + 23592960;                      // 2621440
  float* coeff = W + 26214400;                      // 655360  [m][y][n][e][2]
  float* mo    = W + 26869760;                      // 655360  [m][y][n][o][2]
  float* part  = W + 27525120;                      // 327680 used
  float* stats = W + 28180480;                      // 1280
  float* Keff  = W + 28181760;                      // 4096
  float* twFwH = W + 28185856;                      // 8192
  float* twBwH = W + 28194048;                      // 8192
  _Float16* Tspec = (_Float16*)(W + 28202240);      // 8192 halves
  _Float16* TdftW = (_Float16*)(W + 28206336);      // 8192 halves
  unsigned* Wt   = (unsigned*)(W + 28210432);       // 8388608 u32 (33.5 MB)

  k_tables<<<96,256,0,stream>>>(twFwH, twBwH, Tspec, TdftW);
  k_foldK<<<4,256,0,stream>>>(smw, upw, upb, Keff);
  k_transW<<<512,256,0,stream>>>(fwr, fwi, Wt);
  k_statconv<<<640,256,0,stream>>>(sv, Keff, part);
  k_stats2<<<640,256,0,stream>>>(part, stats);
  k_convnorm<<<1280,256,0,stream>>>(sv, Keff, stats, actA);

  _Float16* xa = actA; _Float16* xb = actB;
  for (int l=0;l<4;++l){
    k_dftW_mfma<<<640,256,0,stream>>>(xa, TdftW, Cy);
    k_dftH<<<640,256,0,stream>>>(Cy, twFwH, coeff);
    k_modemix2<<<512,256,0,stream>>>(coeff, Wt, mo, l);
    k_idftH<<<640,256,0,stream>>>(mo, twBwH, G);
    k_combine_mfma<<<1280,256,0,stream>>>(xa, G, Tspec, fcw + (size_t)l*4096, fcb + (size_t)l*64, xb);
    _Float16* t = xa; xa = xb; xb = t;
  }
  k_downdim<<<1280,256,0,stream>>>(xa, ddw, ddb, out);
}

// Round 7
// 595.628 us; speedup vs baseline: 1.0669x; 1.0122x over previous
//
#include <hip/hip_runtime.h>
#include <math.h>

#define PI_D 3.14159265358979323846

// N=10 images, E=64 ch, H=128, W=256, M=16 modes, L=4 layers

typedef _Float16 h8 __attribute__((ext_vector_type(8)));
typedef float f16v __attribute__((ext_vector_type(16)));

__device__ __forceinline__ float gelu_f(float v){
  return 0.5f*v*(1.0f + erff(v*0.70710678118654752440f));
}

// ---------------- tables ----------------
// twFwH: [h 128][m 32][2]  e^{-2pi i x_m h /128}
// twBwH: [h 128][m 32][2]  e^{+2pi i x_m h /128}   (LAYOUT: h-major for k_spectral phase C)
// Tspec (fp16): [w 256][kk 32], kk=2y+c: c0=cos(2pi w y/256), c1=-sin(2pi w y/256)
// TdftW (fp16): [y2 32][w 256]
__global__ __launch_bounds__(256) void k_tables(float* __restrict__ twFwH, float* __restrict__ twBwH,
                                                _Float16* __restrict__ Tspec, _Float16* __restrict__ TdftW){
  int id = blockIdx.x*256 + threadIdx.x;
  if (id < 4096){
    int h = id >> 5, m = id & 31;
    int xm = (m < 16) ? m : (96 + m);
    double ang = -2.0*PI_D*(double)((xm*h) & 127)/128.0;
    twFwH[id*2]   = (float)cos(ang);
    twFwH[id*2+1] = (float)sin(ang);
  } else if (id < 8192){
    int j = id - 4096;
    int h = j >> 5, m = j & 31;          // h-major now
    int xm = (m < 16) ? m : (96 + m);
    double ang = 2.0*PI_D*(double)((xm*h) & 127)/128.0;
    twBwH[j*2]   = (float)cos(ang);
    twBwH[j*2+1] = (float)sin(ang);
  } else if (id < 16384){
    int j = id - 8192;
    int w = j >> 5, kk = j & 31;
    int y = kk >> 1;
    double ang = 2.0*PI_D*(double)((w*y) & 255)/256.0;
    double v = (kk & 1) ? -sin(ang) : cos(ang);
    Tspec[j] = (_Float16)v;
  } else if (id < 24576){
    int j = id - 16384;
    int y2 = j >> 8, w = j & 255;
    int y = y2 >> 1;
    double ang = -2.0*PI_D*(double)((w*y) & 255)/256.0;
    double v = (y2 & 1) ? sin(ang) : cos(ang);
    TdftW[j] = (_Float16)v;
  }
}

// ---------------- fold updim into collapsed conv: Keff[o][rs*4+tap][4] = {c0,c1,kb,0} ----------------
__global__ __launch_bounds__(256) void k_foldK(const float* __restrict__ smw, const float* __restrict__ upw,
                                               const float* __restrict__ upb, float* __restrict__ Keff){
  int id = blockIdx.x*256 + threadIdx.x;
  if (id >= 1024) return;
  int o = id >> 4, rs = (id >> 2) & 3, tap = id & 3;
  int r = rs >> 1, s = rs & 1, a = tap >> 1, b = tap & 1;
  int klo = (r==0) ? (a==0?0:1) : (a==0?0:2);
  int khi = (r==0) ? (a==0?0:2) : (a==0?1:2);
  int llo = (s==0) ? (b==0?0:1) : (b==0?0:2);
  int lhi = (s==0) ? (b==0?0:2) : (b==0?1:2);
  float a0=0.f, a1=0.f, ab=0.f;
  for (int i=0;i<64;++i){
    float t = 0.f;
    for (int kh=klo; kh<=khi; ++kh)
      for (int kw=llo; kw<=lhi; ++kw)
        t += smw[((size_t)o*64+i)*9 + kh*3+kw];
    a0 += t*upw[i*2];
    a1 += t*upw[i*2+1];
    ab += t*upb[i];
  }
  *(float4*)(Keff + o*64 + (rs*4+tap)*4) = make_float4(a0, a1, ab, 0.f);
}

// ---------------- one-shot weight transpose: wr/wi -> Wt fp16 [l][blk][my][i][o](r,i) ----------------
__global__ __launch_bounds__(256) void k_transW(const float* __restrict__ wr, const float* __restrict__ wi,
                                                unsigned* __restrict__ Wt){
  __shared__ unsigned P[64*257];
  int lb = blockIdx.x;
  int i = lb & 63, blk = (lb>>6)&1, l = lb>>7;
  int tid = threadIdx.x;     // my = mm*16+y
  size_t sbase = (size_t)l*2097152 + (size_t)blk*1048576 + (size_t)i*16384 + tid;
  for (int o=0;o<64;++o){
    float a = wr[sbase + (size_t)o*256];
    float b = wi[sbase + (size_t)o*256];
    union { unsigned u; _Float16 h[2]; } pk;
    pk.h[0] = (_Float16)a; pk.h[1] = (_Float16)b;
    P[o*257 + tid] = pk.u;
  }
  __syncthreads();
  int o = tid & 63, g = tid >> 6;
  size_t dbase = (size_t)(l*2+blk)*1048576;
  for (int it=0; it<64; ++it){
    int my = g*64 + it;
    Wt[dbase + (size_t)my*4096 + i*64 + o] = P[o*257 + my];
  }
}

// ---------------- fused updim+conv statistics, lane = o, 4 col-quarter waves ----------------
// grid 1280 = n*128 + p
__global__ __launch_bounds__(256) void k_statconv(const float* __restrict__ sv,
                                                  const float* __restrict__ Keff,
                                                  float* __restrict__ part){
  __shared__ __align__(16) float SV[6*264]; // [row 3][ch 2][264]
  int bid = blockIdx.x;
  int p = bid & 127, n = bid >> 7;
  int tid = threadIdx.x;
  for (int t = tid; t < 1560; t += 256){
    int dr = t / 520; int rem = t - dr*520; int ch = rem / 260; int ci = rem - ch*260;
    int row = p - 1 + dr, col = ci - 1;
    float v = 0.f;
    if (row >= 0 && row < 128 && col >= 0 && col < 256)
      v = sv[((size_t)(n*2+ch)*128 + row)*256 + col];
    SV[(dr*2+ch)*264 + ci] = v;
  }
  __syncthreads();
  int lane = tid & 63, wid = tid >> 6;
  int c0 = wid * 64;
  float kx[16], ky[16], kz[16];
  #pragma unroll
  for (int t2=0;t2<16;++t2){
    float4 kv = *(const float4*)(Keff + lane*64 + t2*4);
    kx[t2]=kv.x; ky[t2]=kv.y; kz[t2]=kv.z;
  }
  float kzs[4];
  #pragma unroll
  for (int rs=0;rs<4;++rs)
    kzs[rs] = kz[rs*4]+kz[rs*4+1]+kz[rs*4+2]+kz[rs*4+3];
  bool rowedge = (p==0) || (p==127);
  float rok[3]; rok[0] = (p>0)?1.f:0.f; rok[1]=1.f; rok[2]=(p<127)?1.f:0.f;
  float s1=0.f, s2=0.f;
  for (int gq=0; gq<16; ++gq){
    int qq0 = c0 + gq*4;
    float X0[3][8], X1[3][8];
    #pragma unroll
    for (int dr=0; dr<3; ++dr){
      const float* r0 = SV + (dr*2+0)*264 + qq0;
      const float* r1 = SV + (dr*2+1)*264 + qq0;
      float4 a = *(const float4*)r0, b = *(const float4*)(r0+4);
      float4 cc = *(const float4*)r1, d = *(const float4*)(r1+4);
      X0[dr][0]=a.x;X0[dr][1]=a.y;X0[dr][2]=a.z;X0[dr][3]=a.w;
      X0[dr][4]=b.x;X0[dr][5]=b.y;X0[dr][6]=b.z;X0[dr][7]=b.w;
      X1[dr][0]=cc.x;X1[dr][1]=cc.y;X1[dr][2]=cc.z;X1[dr][3]=cc.w;
      X1[dr][4]=d.x;X1[dr][5]=d.y;X1[dr][6]=d.z;X1[dr][7]=d.w;
    }
    bool coledge = (qq0 == 0) || (qq0 == 252);
    if (!coledge && !rowedge){
      #pragma unroll
      for (int j=0;j<4;++j){
        #pragma unroll
        for (int rs=0;rs<4;++rs){
          int r = rs>>1, s = rs&1;
          float y = kzs[rs];
          #pragma unroll
          for (int a2=0;a2<2;++a2)
            #pragma unroll
            for (int b2=0;b2<2;++b2){
              int t2 = rs*4 + a2*2 + b2;
              y += kx[t2]*X0[r+a2][j+s+b2] + ky[t2]*X1[r+a2][j+s+b2];
            }
          s1 += y; s2 = fmaf(y,y,s2);
        }
      }
    } else {
      #pragma unroll
      for (int j=0;j<4;++j){
        int col = qq0 + j;
        float cok[3]; cok[0]=(col>0)?1.f:0.f; cok[1]=1.f; cok[2]=(col<255)?1.f:0.f;
        #pragma unroll
        for (int rs=0;rs<4;++rs){
          int r = rs>>1, s = rs&1;
          float y = 0.f;
          #pragma unroll
          for (int a2=0;a2<2;++a2)
            #pragma unroll
            for (int b2=0;b2<2;++b2){
              int t2 = rs*4 + a2*2 + b2;
              y += kx[t2]*X0[r+a2][j+s+b2] + ky[t2]*X1[r+a2][j+s+b2] + kz[t2]*(rok[r+a2]*cok[s+b2]);
            }
          s1 += y; s2 = fmaf(y,y,s2);
        }
      }
    }
  }
  part[((size_t)bid*4 + wid)*128 + lane*2]   = s1;
  part[((size_t)bid*4 + wid)*128 + lane*2+1] = s2;
}

// ---------------- instance-norm statistics reduce (512 partials per (n,o)) ----------------
__global__ __launch_bounds__(256) void k_stats2(const float* __restrict__ part, float* __restrict__ stats){
  int n = blockIdx.x >> 6, o = blockIdx.x & 63;
  double a1=0.0, a2=0.0;
  #pragma unroll
  for (int it=0; it<2; ++it){
    int idx = threadIdx.x + it*256;   // p*4 + w
    int bid = n*128 + (idx >> 2);
    int w = idx & 3;
    a1 += (double)part[((size_t)bid*4 + w)*128 + o*2];
    a2 += (double)part[((size_t)bid*4 + w)*128 + o*2+1];
  }
  __shared__ double r1[256], r2[256];
  r1[threadIdx.x]=a1; r2[threadIdx.x]=a2; __syncthreads();
  for (int st=128; st>0; st>>=1){
    if (threadIdx.x<st){ r1[threadIdx.x]+=r1[threadIdx.x+st]; r2[threadIdx.x]+=r2[threadIdx.x+st]; }
    __syncthreads();
  }
  if (threadIdx.x==0){
    double mu  = r1[0] / 131072.0;
    double var = r2[0] / 131072.0 - mu*mu;
    stats[blockIdx.x*2]   = (float)mu;
    stats[blockIdx.x*2+1] = (float)(1.0/sqrt(var + 1e-5));
  }
}

// ---------------- fused updim+conv (parity 0 only) + norm + gelu -> fp16 ----------------
__global__ __launch_bounds__(256) void k_convnorm(const float* __restrict__ sv,
                                                  const float* __restrict__ Keff,
                                                  const float* __restrict__ stats,
                                                  _Float16* __restrict__ act){
  __shared__ float SV[4*260];
  int bid = blockIdx.x;
  int p = bid & 127, n = bid >> 7;
  int tid = threadIdx.x;
  for (int t = tid; t < 1032; t += 256){
    int dr = t / 516;
    int rem = t - dr*516;
    int ch = rem / 258;
    int ci = rem - ch*258;
    int row = p - 1 + dr;
    int col = ci - 1;
    float v = 0.f;
    if (row >= 0 && col >= 0 && col < 256)
      v = sv[((size_t)(n*2+ch)*128 + row)*256 + col];
    SV[(dr*2+ch)*260 + ci] = v;
  }
  __syncthreads();

  int q = tid;
  float x0[4], x1[4], ib[4];
  float rowok0 = (p>0)?1.f:0.f;
  float colok0 = (q>0)?1.f:0.f;
  #pragma unroll
  for (int a=0;a<2;++a)
    #pragma unroll
    for (int b=0;b<2;++b){
      x0[a*2+b] = SV[(a*2+0)*260 + q + b];
      x1[a*2+b] = SV[(a*2+1)*260 + q + b];
      ib[a*2+b] = (a==0?rowok0:1.f) * (b==0?colok0:1.f);
    }

  for (int o=0; o<64; ++o){
    const float4* kp = (const float4*)(Keff + o*64);
    float y = 0.f;
    #pragma unroll
    for (int t=0;t<4;++t){
      float4 kv = kp[t];
      y += kv.x*x0[t] + kv.y*x1[t] + kv.z*ib[t];
    }
    float mu = stats[(n*64+o)*2], istd = stats[(n*64+o)*2+1];
    float v = (y - mu)*istd;
    act[((size_t)(n*64+o)*128 + p)*256 + q] = (_Float16)gelu_f(v);
  }
}

// ---------------- forward DFT along W via MFMA; Cy layout [n][y][h][e][2] ----------------
__global__ __launch_bounds__(256, 2) void k_dftW_mfma(const _Float16* __restrict__ act,
                                                      const _Float16* __restrict__ TdftW,
                                                      float* __restrict__ Cy){
  __shared__ _Float16 Ax[32768]; // act [a 128][w 256] chunk-swizzled
  __shared__ _Float16 Bt[8192];  // T   [y2 32][w 256] chunk-swizzled
  int tid = threadIdx.x;
  int hp = blockIdx.x & 63, n = blockIdx.x >> 6;
  int h0 = hp*2;

  {
    int a = tid >> 1;
    int ws = (tid & 1) * 128;
    int e = a & 63, ht = a >> 6;
    const _Float16* src = act + ((size_t)(n*64+e))*32768 + (size_t)(h0+ht)*256 + ws;
    #pragma unroll
    for (int k=0;k<16;++k){
      h8 v = *(const h8*)(src + k*8);
      int wq = (ws >> 3) + k;
      int chunk = wq ^ (a & 7);
      *(h8*)(Ax + a*256 + chunk*8) = v;
    }
  }
  {
    int y2 = tid & 31, ws = (tid >> 5) * 32;
    const _Float16* src = TdftW + y2*256 + ws;
    #pragma unroll
    for (int k=0;k<4;++k){
      h8 v = *(const h8*)(src + k*8);
      int wq = (ws >> 3) + k;
      int chunk = wq ^ (y2 & 7);
      *(h8*)(Bt + y2*256 + chunk*8) = v;
    }
  }
  __syncthreads();

  int lane = tid & 63;
  int l31 = lane & 31, l5 = lane >> 5;
  int mt = tid >> 6;
  int a = mt*32 + l31;

  // D[y2-row][a-col]: A = T (rows y2), B = act^T (cols a)
  f16v acc;
  #pragma unroll
  for (int j=0;j<16;++j) acc[j] = 0.f;
  #pragma unroll
  for (int ks=0;ks<16;++ks){
    int kb = ks*16 + l5*8;
    int cA = (kb>>3) ^ (a & 7);
    int cB = (kb>>3) ^ (l31 & 7);
    h8 af = *(const h8*)(Ax + a*256 + cA*8);   // B operand fragment (col=a)
    h8 bf = *(const h8*)(Bt + l31*256 + cB*8); // A operand fragment (row=y2)
    acc = __builtin_amdgcn_mfma_f32_32x32x16_f16(bf, af, acc, 0,0,0);
  }
  int e = a & 63, ht = a >> 6;
  #pragma unroll
  for (int j=0;j<16;j+=2){
    int y2 = (j&3) + 8*(j>>2) + 4*l5;   // even
    int yy = y2 >> 1;
    *(float2*)(Cy + (((size_t)(n*16+yy)*128 + h0+ht)*64 + e)*2) = make_float2(acc[j], acc[j+1]);
  }
}

// ---------------- fused spectral chain: dftH + modemix + idftH ----------------
// grid 160 = n*16 + y; 1024 threads = 16 waves; G layout [n][h][y][c][o]
__global__ __launch_bounds__(1024) void k_spectral(const float* __restrict__ Cy,
                                                   const float* __restrict__ twF,
                                                   const float* __restrict__ twB,
                                                   const unsigned* __restrict__ Wt,
                                                   float* __restrict__ G, int l){
  __shared__ float CA[8192];   // [hq 2][m 32][i 64][c 2]
  __shared__ float MS[4096];   // [m 32][o 64][c 2]
  int tid = threadIdx.x;
  int lane = tid & 63;
  int wid = __builtin_amdgcn_readfirstlane(tid >> 6);
  int y = blockIdx.x & 15, n = blockIdx.x >> 4;

  // ---- phase A: coeff[m][e] = sum_h twF[h][m] * Cy[h][e], split over 2 h-halves ----
  {
    int m4 = (wid & 7)*4, hq = wid >> 3;
    const float* cyb = Cy + (((size_t)(n*16+y)*128 + hq*64)*64 + lane)*2;
    float ar[4], ai[4];
    #pragma unroll
    for (int mm=0;mm<4;++mm){ ar[mm]=0.f; ai[mm]=0.f; }
    for (int hh=0; hh<64; ++hh){
      float2 c = *(const float2*)(cyb + hh*128);
      const float* tp = twF + (((hq*64+hh)*32) + m4)*2;   // wave-uniform -> s_load
      #pragma unroll
      for (int mm=0;mm<4;++mm){
        float tr = tp[mm*2], ti = tp[mm*2+1];
        ar[mm] += tr*c.x - ti*c.y;
        ai[mm] += tr*c.y + ti*c.x;
      }
    }
    #pragma unroll
    for (int mm=0;mm<4;++mm)
      *(float2*)(CA + ((hq*32 + m4+mm)*64 + lane)*2) = make_float2(ar[mm], ai[mm]);
  }
  __syncthreads();

  // ---- phase B: mo[m][o] = sum_i coeff[m][i] * W[my][i][o] (complex) ----
  {
    #pragma unroll
    for (int t2=0; t2<2; ++t2){
      int m = wid*2 + t2;
      int blk = m >> 4, mm = m & 15;
      int my = mm*16 + y;
      const unsigned* wb = Wt + ((size_t)((l*2+blk)*256 + my))*4096 + lane;
      float mr = 0.f, mi = 0.f;
      for (int i=0;i<64;++i){
        float2 cA0 = *(const float2*)(CA + ((m)*64 + i)*2);
        float2 cA1 = *(const float2*)(CA + ((32+m)*64 + i)*2);
        float cr = cA0.x + cA1.x, ci2 = cA0.y + cA1.y;
        union { unsigned u; _Float16 h[2]; } pk;
        pk.u = wb[(size_t)i*64];
        float wr_f = (float)pk.h[0], wi_f = (float)pk.h[1];
        mr += cr*wr_f - ci2*wi_f;
        mi += cr*wi_f + ci2*wr_f;
      }
      *(float2*)(MS + (m*64 + lane)*2) = make_float2(mr, mi);
    }
  }
  __syncthreads();

  // ---- phase C: G[h][o] = sum_m twB[h][m] * mo[m][o], alpha/norm folded ----
  {
    float f = (y==0) ? (1.f/32768.f) : (2.f/32768.f);
    for (int k=0;k<8;++k){
      int h = wid*8 + k;
      const float* tb = twB + h*64;   // wave-uniform
      float gr=0.f, gi=0.f;
      #pragma unroll
      for (int m=0;m<32;++m){
        float tr = tb[m*2], ti = tb[m*2+1];
        float2 mo2 = *(const float2*)(MS + (m*64+lane)*2);
        gr += tr*mo2.x - ti*mo2.y;
        gi += tr*mo2.y + ti*mo2.x;
      }
      size_t gb = (((size_t)(n*128+h)*16 + y)*2)*64 + lane;
      G[gb]      = gr*f;
      G[gb + 64] = gi*f;
    }
  }
}

// ---------------- fused skip-GEMM + inverse DFT-W + gelu via MFMA ----------------
// G layout [n][h][y][c][o]: contiguous 2048-float slice per (n,h)
__global__ __launch_bounds__(256, 2) void k_combine_mfma(const _Float16* __restrict__ act_in,
                                                         const float* __restrict__ G,
                                                         const _Float16* __restrict__ Tspec,
                                                         const float* __restrict__ cw,
                                                         const float* __restrict__ cb,
                                                         _Float16* __restrict__ act_out){
  __shared__ _Float16 Bx[32768]; // [w 256][k 128] chunk-swizzled
  __shared__ _Float16 At[8192];  // [o 64][k 128] chunk-swizzled
  int tid = threadIdx.x;
  int h = blockIdx.x & 127, n = blockIdx.x >> 7;

  {
    int p = tid >> 3;
    int wl = tid & 7;
    int i0 = 2*p;
    const _Float16* r0 = act_in + (size_t)(n*64+i0)*32768 + (size_t)h*256;
    const _Float16* r1 = r0 + 32768;
    int cbase = (p >> 2);
    #pragma unroll
    for (int jj=0; jj<32; ++jj){
      int w = wl + 8*jj;
      union { _Float16 hh[2]; unsigned u; } pk;
      pk.hh[0] = r0[w]; pk.hh[1] = r1[w];
      int chunk = cbase ^ (w & 7);
      *(unsigned*)(Bx + w*128 + chunk*8 + (i0 & 7)) = pk.u;
    }
  }
  {
    int o = tid >> 2, seg = (tid & 3)*16;
    float4 c0 = *(const float4*)(cw + o*64 + seg);
    float4 c1 = *(const float4*)(cw + o*64 + seg + 4);
    float4 c2 = *(const float4*)(cw + o*64 + seg + 8);
    float4 c3 = *(const float4*)(cw + o*64 + seg + 12);
    h8 v0, v1;
    v0[0]=(_Float16)c0.x; v0[1]=(_Float16)c0.y; v0[2]=(_Float16)c0.z; v0[3]=(_Float16)c0.w;
    v0[4]=(_Float16)c1.x; v0[5]=(_Float16)c1.y; v0[6]=(_Float16)c1.z; v0[7]=(_Float16)c1.w;
    v1[0]=(_Float16)c2.x; v1[1]=(_Float16)c2.y; v1[2]=(_Float16)c2.z; v1[3]=(_Float16)c2.w;
    v1[4]=(_Float16)c3.x; v1[5]=(_Float16)c3.y; v1[6]=(_Float16)c3.z; v1[7]=(_Float16)c3.w;
    int cb0 = (seg>>3) ^ (o & 7);
    int cb1 = ((seg>>3)+1) ^ (o & 7);
    *(h8*)(At + o*128 + cb0*8) = v0;
    *(h8*)(At + o*128 + cb1*8) = v1;
  }
  {
    // G staging: contiguous slice, thread reads 8 floats
    const float* gp = G + (size_t)(n*128 + h)*2048 + tid*8;
    float4 g0 = *(const float4*)gp;
    float4 g1 = *(const float4*)(gp + 4);
    float gv[8] = {g0.x,g0.y,g0.z,g0.w,g1.x,g1.y,g1.z,g1.w};
    int idx0 = tid*8;
    int yc = idx0 >> 6;          // 2y+c (uniform over the 8 values)
    int o0 = idx0 & 63;
    int kk = 64 + yc;
    #pragma unroll
    for (int j=0;j<8;++j){
      int o = o0 + j;
      int chunk = (kk >> 3) ^ (o & 7);
      At[o*128 + chunk*8 + (kk & 7)] = (_Float16)gv[j];
    }
  }
  {
    int w = tid;
    const _Float16* tp = Tspec + w*32;
    #pragma unroll
    for (int cc=0; cc<4; ++cc){
      h8 v = *(const h8*)(tp + cc*8);
      int chunk = (8 + cc) ^ (w & 7);
      *(h8*)(Bx + w*128 + chunk*8) = v;
    }
  }
  __syncthreads();

  int lane = tid & 63;
  int l31 = lane & 31, l5 = lane >> 5;
  int w0 = tid >> 6;
  int mt = w0 & 1, ng = w0 >> 1;
  int o_lane = mt*32 + l31;

  h8 af[6];
  #pragma unroll
  for (int ks=0;ks<6;++ks){
    int kb = ks*16 + l5*8;
    int chunk = (kb>>3) ^ (o_lane & 7);
    af[ks] = *(const h8*)(At + o_lane*128 + chunk*8);
  }
  float bias[16];
  #pragma unroll
  for (int j=0;j<16;++j) bias[j] = cb[mt*32 + (j&3) + 8*(j>>2) + 4*l5];

  f16v acc[4];
  #pragma unroll
  for (int q=0;q<4;++q)
    #pragma unroll
    for (int j=0;j<16;++j) acc[q][j] = bias[j];

  #pragma unroll
  for (int q=0;q<4;++q){
    int w = (ng*4+q)*32 + l31;
    const _Float16* bbase = Bx + w*128;
    int w7 = w & 7;
    #pragma unroll
    for (int ks=0;ks<6;++ks){
      int kb = ks*16 + l5*8;
      int chunk = (kb>>3) ^ w7;
      h8 bf = *(const h8*)(bbase + chunk*8);
      acc[q] = __builtin_amdgcn_mfma_f32_32x32x16_f16(af[ks], bf, acc[q], 0,0,0);
    }
  }

  #pragma unroll
  for (int q=0;q<4;++q){
    int wcol = (ng*4+q)*32 + l31;
    #pragma unroll
    for (int j=0;j<16;++j){
      int o = mt*32 + (j&3) + 8*(j>>2) + 4*l5;
      float v = gelu_f(acc[q][j]);
      act_out[(size_t)(n*64+o)*32768 + (size_t)h*256 + wcol] = (_Float16)v;
    }
  }
}

// ---------------- downdim 1x1 conv (E=64 -> C=2), fp16 in ----------------
__global__ __launch_bounds__(256) void k_downdim(const _Float16* __restrict__ x, const float* __restrict__ wd,
                                                 const float* __restrict__ bd, float* __restrict__ out){
  size_t idx = (size_t)blockIdx.x*256 + threadIdx.x;
  int n = (int)(idx >> 15);
  int pos = (int)(idx & 32767);
  float a0 = bd[0], a1 = bd[1];
  const _Float16* xp = x + (size_t)n*2097152 + pos;
  for (int e=0;e<64;++e){
    float v = (float)xp[(size_t)e*32768];
    a0 += wd[e]*v;
    a1 += wd[64+e]*v;
  }
  out[(size_t)n*65536 + pos] = a0;
  out[(size_t)n*65536 + 32768 + pos] = a1;
}

extern "C" void kernel_launch(void* const* d_in, const int* in_sizes, int n_in,
                              void* d_out, int out_size, void* d_ws, size_t ws_size,
                              hipStream_t stream) {
  const float* sv  = (const float*)d_in[0];
  const float* upw = (const float*)d_in[1];
  const float* upb = (const float*)d_in[2];
  const float* smw = (const float*)d_in[3];
  const float* smb = (const float*)d_in[4];
  const float* fwr = (const float*)d_in[5];
  const float* fwi = (const float*)d_in[6];
  const float* fcw = (const float*)d_in[7];
  const float* fcb = (const float*)d_in[8];
  const float* ddw = (const float*)d_in[9];
  const float* ddb = (const float*)d_in[10];
  float* out = (float*)d_out;
  (void)smb; // spatially uniform per (n,o); cancelled exactly by instance-norm mean subtraction

  float* W = (float*)d_ws;
  _Float16* actA = (_Float16*)W;                    // 20971520 halves
  _Float16* actB = (_Float16*)(W + 10485760);       // 20971520 halves
  float* Cy    = W + 20971520;                      // 2621440  [n][y][h][e][2]
  float* G     = W + 23592960;                      // 2621440  [n][h][y][c][o]
  float* part  = W + 26214400;                      // 655360 used
  float* stats = W + 28180480;                      // 1280
  float* Keff  = W + 28181760;                      // 4096
  float* twFwH = W + 28185856;                      // 8192
  float* twBwH = W + 28194048;                      // 8192
  _Float16* Tspec = (_Float16*)(W + 28202240);      // 8192 halves
  _Float16* TdftW = (_Float16*)(W + 28206336);      // 8192 halves
  unsigned* Wt   = (unsigned*)(W + 28210432);       // 8388608 u32 (33.5 MB)

  k_tables<<<96,256,0,stream>>>(twFwH, twBwH, Tspec, TdftW);
  k_foldK<<<4,256,0,stream>>>(smw, upw, upb, Keff);
  k_transW<<<512,256,0,stream>>>(fwr, fwi, Wt);
  k_statconv<<<1280,256,0,stream>>>(sv, Keff, part);
  k_stats2<<<640,256,0,stream>>>(part, stats);
  k_convnorm<<<1280,256,0,stream>>>(sv, Keff, stats, actA);

  _Float16* xa = actA; _Float16* xb = actB;
  for (int l=0;l<4;++l){
    k_dftW_mfma<<<640,256,0,stream>>>(xa, TdftW, Cy);
    k_spectral<<<160,1024,0,stream>>>(Cy, twFwH, twBwH, Wt, G, l);
    k_combine_mfma<<<1280,256,0,stream>>>(xa, G, Tspec, fcw + (size_t)l*4096, fcb + (size_t)l*64, xb);
    _Float16* t = xa; xa = xb; xb = t;
  }
  k_downdim<<<1280,256,0,stream>>>(xa, ddw, ddb, out);
}